// Round 4
// baseline (162.423 us; speedup 1.0000x reference)
//
#include <hip/hip_runtime.h>
#include <hip/hip_bf16.h>

// All inputs/outputs fp32 (established rounds 1-2).
constexpr int B = 2, S = 2048, E = 1024, H = 16, D = 64;
constexpr int E4 = E / 4;  // 256 float4 per row

// ---------------------------------------------------------------------------
// K1: fused q-projection + wkq + rowsum zero.
// grid (B, H, 2) x 256. Stage 1: qh[d] = x[b,-1,:] . Wq[h*64+d,:]
// Stage 2: wkq[b,h,e] = sum_d qh[d] * Wk[h*64+d, e] for e-slice of 512.
__global__ __launch_bounds__(256) void k_qwkq(const float4* __restrict__ x4,
                                              const float4* __restrict__ Wq4,
                                              const float* __restrict__ Wk,
                                              float* __restrict__ wkq,
                                              float* __restrict__ rowsum) {
  int b = blockIdx.x, h = blockIdx.y, eo = blockIdx.z;
  int t = threadIdx.x;
  __shared__ float qred[64][4];
  __shared__ float qh[64];
  const float4* xr = x4 + ((size_t)b * S + (S - 1)) * E4;
  {
    int n = t >> 2, part = t & 3;
    const float4* wr = Wq4 + (size_t)(h * 64 + n) * E4 + part * 64;
    const float4* xp = xr + part * 64;
    float acc = 0.f;
#pragma unroll 8
    for (int j = 0; j < 64; ++j) {
      float4 a = xp[j], w = wr[j];
      acc += a.x * w.x + a.y * w.y + a.z * w.z + a.w * w.w;
    }
    qred[n][part] = acc;
  }
  __syncthreads();
  if (t < 64) qh[t] = qred[t][0] + qred[t][1] + qred[t][2] + qred[t][3];
  if (t == 0 && eo == 0) rowsum[b * H + h] = 0.f;
  __syncthreads();
  int e = eo * 512 + t;
  const float* wp = Wk + (size_t)(h * 64) * E + e;
  float a0 = 0.f, a1 = 0.f;
#pragma unroll 8
  for (int d = 0; d < 64; ++d) {
    float q = qh[d];
    a0 += q * wp[(size_t)d * E];
    a1 += q * wp[(size_t)d * E + 256];
  }
  int bh = b * H + h;
  wkq[(size_t)bh * E + e] = a0;
  wkq[(size_t)bh * E + e + 256] = a1;
}

// ---------------------------------------------------------------------------
// K2: p[b,h,k] = exp(embK[b,k,:] . wkq[b,h,:])  (UNSCALED softmax numerator;
// scores are O(+-15) so no max-subtraction needed in fp32), plus rowsum
// accumulation. grid 256 x 256; wkq[b] (64KB) in LDS; embK slice in regs.
__global__ __launch_bounds__(256) void k_scores_exp(const float4* __restrict__ embK,
                                                    const float4* __restrict__ wkq4,
                                                    float* __restrict__ p,
                                                    float* __restrict__ rowsum) {
  __shared__ float4 wl[H * E4];  // 64 KB
  __shared__ float hsum[16];
  int blk = blockIdx.x;
  int b = blk >> 7, k0 = (blk & 127) * 16;
  int tid = threadIdx.x;
#pragma unroll
  for (int j = 0; j < 16; ++j)
    wl[j * 256 + tid] = wkq4[(size_t)b * (H * E4) + j * 256 + tid];
  if (tid < 16) hsum[tid] = 0.f;
  __syncthreads();
  int k = tid >> 4, es = tid & 15;
  const float4* er = embK + ((size_t)b * S + k0 + k) * E4;
  float4 v[16];
#pragma unroll
  for (int j = 0; j < 16; ++j) v[j] = er[es + 16 * j];
#pragma unroll 1
  for (int h = 0; h < H; ++h) {
    float acc = 0.f;
#pragma unroll
    for (int j = 0; j < 16; ++j) {
      float4 w = wl[h * 256 + es + 16 * j];
      acc += v[j].x * w.x + v[j].y * w.y + v[j].z * w.z + v[j].w * w.w;
    }
#pragma unroll
    for (int o = 8; o > 0; o >>= 1) acc += __shfl_xor(acc, o, 64);
    if (es == 0) {
      float pe = __expf(acc);
      p[((size_t)(b * H + h)) * S + k0 + k] = pe;
      atomicAdd(&hsum[h], pe);
    }
  }
  __syncthreads();
  if (tid < 16) atomicAdd(&rowsum[b * H + tid], hsum[tid]);
}

// ---------------------------------------------------------------------------
// K3: deterministic partial ctx (no global atomics).
// grid (B, 4, 16) x 256: e4-slice of 64 x k-chunk of 128; the 4 waves split
// the k-chunk (32 each) and write separate partials pz = kz*4 + wave.
// part[pz][b][h][e4] : 64 partials x 32768 floats = 8 MB ws.
__global__ __launch_bounds__(256) void k_ctx_part(const float4* __restrict__ embV,
                                                  const float* __restrict__ p,
                                                  const float* __restrict__ rowsum,
                                                  float4* __restrict__ part) {
  int b = blockIdx.x, eo = blockIdx.y, kz = blockIdx.z;
  int tid = threadIdx.x;
  int e4l = tid & 63, w = tid >> 6;
  int k0 = kz * 128;
  __shared__ float pl[16 * 128];  // 8 KB
  __shared__ float sinv[16];
  if (tid < 16) sinv[tid] = 1.f / rowsum[b * H + tid];
  __syncthreads();
  for (int i = tid; i < 16 * 128; i += 256) {
    int h = i >> 7, kk = i & 127;
    pl[i] = p[((size_t)(b * H + h)) * S + k0 + kk] * sinv[h];
  }
  __syncthreads();
  int e4 = eo * 64 + e4l;
  float4 acc[H];
#pragma unroll
  for (int h = 0; h < H; ++h) acc[h] = make_float4(0.f, 0.f, 0.f, 0.f);
  int kb = w * 32;
  for (int i = 0; i < 32; ++i) {
    int kk = kb + i;
    float4 v = embV[((size_t)b * S + k0 + kk) * E4 + e4];
#pragma unroll
    for (int h = 0; h < H; ++h) {
      float pv = pl[h * 128 + kk];  // wave-uniform address -> free broadcast
      acc[h].x += pv * v.x; acc[h].y += pv * v.y;
      acc[h].z += pv * v.z; acc[h].w += pv * v.w;
    }
  }
  int pz = kz * 4 + w;
#pragma unroll
  for (int h = 0; h < H; ++h)
    part[((size_t)(pz * B + b) * H + h) * E4 + e4] = acc[h];
}

// ---------------------------------------------------------------------------
// K4: fused partial-reduce + Wv matvec.
// grid (B, H) x 256. Reduce 64 partials into LDS ctx row (1024 floats),
// then o_vec[b, h*64+n] = ctx_row . Wv[h*64+n, :].
__global__ __launch_bounds__(256) void k_ovec(const float4* __restrict__ part,
                                              const float4* __restrict__ Wv4,
                                              float* __restrict__ o_vec) {
  int b = blockIdx.x, h = blockIdx.y;
  int t = threadIdx.x;
  __shared__ float4 crow[E4];  // 4 KB
  float4 acc = make_float4(0.f, 0.f, 0.f, 0.f);
  const float4* pp = part + ((size_t)b * H + h) * E4 + t;
  const size_t pstride = (size_t)B * H * E4;
#pragma unroll 8
  for (int pz = 0; pz < 64; ++pz) {
    float4 c = pp[pz * pstride];
    acc.x += c.x; acc.y += c.y; acc.z += c.z; acc.w += c.w;
  }
  crow[t] = acc;
  __syncthreads();
  int n_l = t >> 2, p4 = t & 3;
  const float4* wr = Wv4 + (size_t)(h * 64 + n_l) * E4 + p4 * 64;
  float a = 0.f;
#pragma unroll 8
  for (int j = 0; j < 64; ++j) {
    float4 c = crow[p4 * 64 + j];
    float4 w = wr[j];
    a += c.x * w.x + c.y * w.y + c.z * w.z + c.w * w.w;
  }
  a += __shfl_xor(a, 1, 64);
  a += __shfl_xor(a, 2, 64);
  if (p4 == 0) o_vec[(size_t)b * E + h * 64 + n_l] = a;
}

// ---------------------------------------------------------------------------
// K5: out_vec[b*E+n] = o_vec[b,:] . Wo[n,:]  (wave per n)
__global__ void k_outvec(const float* __restrict__ o_vec, const float4* __restrict__ Wo4,
                         float* __restrict__ out_vec) {
  int gw = (blockIdx.x * blockDim.x + threadIdx.x) >> 6;
  int lane = threadIdx.x & 63;
  int b = gw >> 10, nn = gw & 1023;
  const float4* xr = (const float4*)(o_vec + (size_t)b * E);
  const float4* wr = Wo4 + (size_t)nn * E4;
  float acc = 0.f;
#pragma unroll
  for (int j = 0; j < 4; ++j) {
    float4 a = xr[lane + 64 * j];
    float4 w = wr[lane + 64 * j];
    acc += a.x * w.x + a.y * w.y + a.z * w.z + a.w * w.w;
  }
#pragma unroll
  for (int o = 32; o > 0; o >>= 1) acc += __shfl_xor(acc, o, 64);
  if (lane == 0) out_vec[gw] = acc;
}

// ---------------------------------------------------------------------------
// K6: broadcast out_vec over all S rows (float4, write-bound ~2.7 us).
__global__ void k_bcast(const float4* __restrict__ ov4, float4* __restrict__ out4) {
  int base = blockIdx.x * 1024 + threadIdx.x;
#pragma unroll
  for (int r = 0; r < 4; ++r) {
    int g = base + r * 256;
    out4[g] = ov4[(g >> 19) * E4 + (g & 255)];
  }
}

// ---------------------------------------------------------------------------
extern "C" void kernel_launch(void* const* d_in, const int* in_sizes, int n_in,
                              void* d_out, int out_size, void* d_ws, size_t ws_size,
                              hipStream_t stream) {
  const float* inputs = (const float*)d_in[0];
  const float* embV   = (const float*)d_in[1];
  const float* embK   = (const float*)d_in[2];
  const float* Wq     = (const float*)d_in[3];
  const float* Wk     = (const float*)d_in[4];
  const float* Wv     = (const float*)d_in[5];
  const float* Wo     = (const float*)d_in[6];

  float* ws      = (float*)d_ws;
  float* wkq     = ws;                    // 32768
  float* p       = wkq + B * H * E;       // 65536 (exp scores)
  float* rowsum  = p + B * H * S;         // 32
  float* o_vec   = rowsum + 64;           // 2048
  float* out_vec = o_vec + B * E;         // 2048
  float* part    = out_vec + B * E;       // 64*B*H*E = 2097152 (8 MB)

  k_qwkq<<<dim3(B, H, 2), 256, 0, stream>>>((const float4*)inputs, (const float4*)Wq,
                                            Wk, wkq, rowsum);
  k_scores_exp<<<256, 256, 0, stream>>>((const float4*)embK, (const float4*)wkq,
                                        p, rowsum);
  k_ctx_part<<<dim3(B, 4, 16), 256, 0, stream>>>((const float4*)embV, p, rowsum,
                                                 (float4*)part);
  k_ovec<<<dim3(B, H), 256, 0, stream>>>((const float4*)part, (const float4*)Wv, o_vec);
  k_outvec<<<512, 256, 0, stream>>>(o_vec, (const float4*)Wo, out_vec);
  k_bcast<<<1024, 256, 0, stream>>>((const float4*)out_vec, (float4*)d_out);
}

// Round 5
// 156.667 us; speedup vs baseline: 1.0367x; 1.0367x over previous
//
#include <hip/hip_runtime.h>
#include <hip/hip_bf16.h>

// All inputs/outputs fp32 (established rounds 1-2).
constexpr int B = 2, S = 2048, E = 1024, H = 16, D = 64;
constexpr int E4 = E / 4;  // 256 float4 per row

// ---------------------------------------------------------------------------
// K1: q_vec[b*E + n] = x[b,S-1,:] . Wq[n,:]
// grid 256 x 256; block = (b, 8 consecutive n); 32-lane e-split. (r3 proven)
__global__ void k_qvec(const float4* __restrict__ x, const float4* __restrict__ Wq,
                       float* __restrict__ q_vec) {
  int blk = blockIdx.x;
  int b = blk >> 7, n0 = (blk & 127) * 8;
  int tid = threadIdx.x;
  int nl = tid >> 5, es = tid & 31;
  const float4* xr = x + ((size_t)b * S + (S - 1)) * E4;
  const float4* wr = Wq + (size_t)(n0 + nl) * E4;
  float acc = 0.f;
#pragma unroll
  for (int j = 0; j < 8; ++j) {
    float4 a = xr[es + 32 * j];
    float4 w = wr[es + 32 * j];
    acc += a.x * w.x + a.y * w.y + a.z * w.z + a.w * w.w;
  }
#pragma unroll
  for (int o = 16; o > 0; o >>= 1) acc += __shfl_xor(acc, o, 64);
  if (es == 0) q_vec[b * E + n0 + nl] = acc;
}

// ---------------------------------------------------------------------------
// K2: wkq[b,h,e] = sum_d q_vec[b,h*D+d] * Wk[h*D+d,e]; zeroes rowsum.
// grid 256 = (bh, 8 eo) x 128 thr. (r3 proven)
__global__ void k_wkq(const float* __restrict__ q_vec, const float* __restrict__ Wk,
                      float* __restrict__ wkq, float* __restrict__ rowsum) {
  int blk = blockIdx.x;
  int eo = blk & 7;
  int bh = blk >> 3;
  int h = bh & 15;
  int tid = threadIdx.x;
  __shared__ float qh[D];
  if (tid < D) qh[tid] = q_vec[(bh >> 4) * E + h * D + tid];
  if (eo == 0 && tid == 0) rowsum[bh] = 0.f;
  __syncthreads();
  int e = eo * 128 + tid;
  const float* wp = Wk + (size_t)h * D * E + e;
  float acc = 0.f;
#pragma unroll 8
  for (int d = 0; d < D; ++d) acc += qh[d] * wp[(size_t)d * E];
  wkq[(size_t)bh * E + e] = acc;
}

// ---------------------------------------------------------------------------
// K3: p[b,h,k] = exp(embK[b,k,:] . wkq[b,h,:]) + per-row sums.
// LDS-BW-bound redesign: 2 embK rows per thread in registers so each
// ds_read_b128 of wl feeds 2 FMAs (268->134 MB LDS traffic).
// grid 256 = (b, 128 k-tiles of 16) x 128 thr; thread = (kp of 8, es of 16),
// rows k0+kp and k0+8+kp.
__global__ __launch_bounds__(128) void k_scores_exp(const float4* __restrict__ embK,
                                                    const float4* __restrict__ wkq4,
                                                    float* __restrict__ p,
                                                    float* __restrict__ rowsum) {
  __shared__ float4 wl[H * E4];  // 64 KB
  __shared__ float hsum[16];
  int blk = blockIdx.x;
  int b = blk >> 7, k0 = (blk & 127) * 16;
  int tid = threadIdx.x;
#pragma unroll
  for (int j = 0; j < 32; ++j)
    wl[j * 128 + tid] = wkq4[(size_t)b * (H * E4) + j * 128 + tid];
  if (tid < 16) hsum[tid] = 0.f;
  __syncthreads();
  int kp = tid >> 4, es = tid & 15;
  int ka = k0 + kp, kb = k0 + 8 + kp;
  const float4* ea = embK + ((size_t)b * S + ka) * E4;
  const float4* eb = embK + ((size_t)b * S + kb) * E4;
  float4 va[16], vb[16];
#pragma unroll
  for (int j = 0; j < 16; ++j) { va[j] = ea[es + 16 * j]; vb[j] = eb[es + 16 * j]; }
#pragma unroll 1
  for (int h = 0; h < H; ++h) {
    float aa = 0.f, ab = 0.f;
#pragma unroll
    for (int j = 0; j < 16; ++j) {
      float4 w = wl[h * 256 + es + 16 * j];
      aa += va[j].x * w.x + va[j].y * w.y + va[j].z * w.z + va[j].w * w.w;
      ab += vb[j].x * w.x + vb[j].y * w.y + vb[j].z * w.z + vb[j].w * w.w;
    }
#pragma unroll
    for (int o = 8; o > 0; o >>= 1) {
      aa += __shfl_xor(aa, o, 64);
      ab += __shfl_xor(ab, o, 64);
    }
    if (es == 0) {
      float pa = __expf(aa), pb = __expf(ab);
      float* pr = p + ((size_t)(b * H + h)) * S;
      pr[ka] = pa;
      pr[kb] = pb;
      atomicAdd(&hsum[h], pa + pb);
    }
  }
  __syncthreads();
  if (tid < 16) atomicAdd(&rowsum[b * H + tid], hsum[tid]);
}

// ---------------------------------------------------------------------------
// K4: deterministic partial ctx (no global atomics).
// grid (B, 4, 16) x 256: e4-slice of 64 x k-chunk of 128; 4 waves split the
// chunk (32 k each), partial pz = kz*4 + wave. part: 64 x B*H*E floats (8 MB).
__global__ __launch_bounds__(256) void k_ctx_part(const float4* __restrict__ embV,
                                                  const float* __restrict__ p,
                                                  const float* __restrict__ rowsum,
                                                  float4* __restrict__ part) {
  int b = blockIdx.x, eo = blockIdx.y, kz = blockIdx.z;
  int tid = threadIdx.x;
  int e4l = tid & 63, w = tid >> 6;
  int k0 = kz * 128;
  __shared__ float pl[16 * 128];  // 8 KB
  __shared__ float sinv[16];
  if (tid < 16) sinv[tid] = 1.f / rowsum[b * H + tid];
  __syncthreads();
  for (int i = tid; i < 16 * 128; i += 256) {
    int h = i >> 7, kk = i & 127;
    pl[i] = p[((size_t)(b * H + h)) * S + k0 + kk] * sinv[h];
  }
  __syncthreads();
  int e4 = eo * 64 + e4l;
  float4 acc[H];
#pragma unroll
  for (int h = 0; h < H; ++h) acc[h] = make_float4(0.f, 0.f, 0.f, 0.f);
  int kb = w * 32;
  for (int i = 0; i < 32; ++i) {
    int kk = kb + i;
    float4 v = embV[((size_t)b * S + k0 + kk) * E4 + e4];
#pragma unroll
    for (int h = 0; h < H; ++h) {
      float pv = pl[h * 128 + kk];  // wave-uniform address -> free broadcast
      acc[h].x += pv * v.x; acc[h].y += pv * v.y;
      acc[h].z += pv * v.z; acc[h].w += pv * v.w;
    }
  }
  int pz = kz * 4 + w;
#pragma unroll
  for (int h = 0; h < H; ++h)
    part[((size_t)(pz * B + b) * H + h) * E4 + e4] = acc[h];
}

// ---------------------------------------------------------------------------
// K5: fused partial-reduce + Wv matvec. grid (B,H) x 256.
__global__ __launch_bounds__(256) void k_ovec(const float4* __restrict__ part,
                                              const float4* __restrict__ Wv4,
                                              float* __restrict__ o_vec) {
  int b = blockIdx.x, h = blockIdx.y;
  int t = threadIdx.x;
  __shared__ float4 crow[E4];  // 4 KB
  float4 acc = make_float4(0.f, 0.f, 0.f, 0.f);
  const float4* pp = part + ((size_t)b * H + h) * E4 + t;
  const size_t pstride = (size_t)B * H * E4;
#pragma unroll 8
  for (int pz = 0; pz < 64; ++pz) {
    float4 c = pp[pz * pstride];
    acc.x += c.x; acc.y += c.y; acc.z += c.z; acc.w += c.w;
  }
  crow[t] = acc;
  __syncthreads();
  int n_l = t >> 2, p4 = t & 3;
  const float4* wr = Wv4 + (size_t)(h * 64 + n_l) * E4 + p4 * 64;
  float a = 0.f;
#pragma unroll 8
  for (int j = 0; j < 64; ++j) {
    float4 c = crow[p4 * 64 + j];
    float4 w = wr[j];
    a += c.x * w.x + c.y * w.y + c.z * w.z + c.w * w.w;
  }
  a += __shfl_xor(a, 1, 64);
  a += __shfl_xor(a, 2, 64);
  if (p4 == 0) o_vec[(size_t)b * E + h * 64 + n_l] = a;
}

// ---------------------------------------------------------------------------
// K6: out_vec[b*E+n] = o_vec[b,:] . Wo[n,:]  (wave per n)
__global__ void k_outvec(const float* __restrict__ o_vec, const float4* __restrict__ Wo4,
                         float* __restrict__ out_vec) {
  int gw = (blockIdx.x * blockDim.x + threadIdx.x) >> 6;
  int lane = threadIdx.x & 63;
  int b = gw >> 10, nn = gw & 1023;
  const float4* xr = (const float4*)(o_vec + (size_t)b * E);
  const float4* wr = Wo4 + (size_t)nn * E4;
  float acc = 0.f;
#pragma unroll
  for (int j = 0; j < 4; ++j) {
    float4 a = xr[lane + 64 * j];
    float4 w = wr[lane + 64 * j];
    acc += a.x * w.x + a.y * w.y + a.z * w.z + a.w * w.w;
  }
#pragma unroll
  for (int o = 32; o > 0; o >>= 1) acc += __shfl_xor(acc, o, 64);
  if (lane == 0) out_vec[gw] = acc;
}

// ---------------------------------------------------------------------------
// K7: broadcast out_vec over all S rows (float4, write-bound ~2.7 us).
__global__ void k_bcast(const float4* __restrict__ ov4, float4* __restrict__ out4) {
  int base = blockIdx.x * 1024 + threadIdx.x;
#pragma unroll
  for (int r = 0; r < 4; ++r) {
    int g = base + r * 256;
    out4[g] = ov4[(g >> 19) * E4 + (g & 255)];
  }
}

// ---------------------------------------------------------------------------
extern "C" void kernel_launch(void* const* d_in, const int* in_sizes, int n_in,
                              void* d_out, int out_size, void* d_ws, size_t ws_size,
                              hipStream_t stream) {
  const float* inputs = (const float*)d_in[0];
  const float* embV   = (const float*)d_in[1];
  const float* embK   = (const float*)d_in[2];
  const float* Wq     = (const float*)d_in[3];
  const float* Wk     = (const float*)d_in[4];
  const float* Wv     = (const float*)d_in[5];
  const float* Wo     = (const float*)d_in[6];

  float* ws      = (float*)d_ws;
  float* q_vec   = ws;                    // 2048
  float* wkq     = q_vec + B * E;         // 32768
  float* p       = wkq + B * H * E;       // 65536 (exp scores)
  float* rowsum  = p + B * H * S;         // 32 (pad to 64)
  float* o_vec   = rowsum + 64;           // 2048
  float* out_vec = o_vec + B * E;         // 2048
  float* part    = out_vec + B * E;       // 64*B*H*E = 2097152 (8 MB)

  k_qvec<<<256, 256, 0, stream>>>((const float4*)inputs, (const float4*)Wq, q_vec);
  k_wkq<<<256, 128, 0, stream>>>(q_vec, Wk, wkq, rowsum);
  k_scores_exp<<<256, 128, 0, stream>>>((const float4*)embK, (const float4*)wkq,
                                        p, rowsum);
  k_ctx_part<<<dim3(B, 4, 16), 256, 0, stream>>>((const float4*)embV, p, rowsum,
                                                 (float4*)part);
  k_ovec<<<dim3(B, H), 256, 0, stream>>>((const float4*)part, (const float4*)Wv, o_vec);
  k_outvec<<<512, 256, 0, stream>>>(o_vec, (const float4*)Wo, out_vec);
  k_bcast<<<1024, 256, 0, stream>>>((const float4*)out_vec, (float4*)d_out);
}

// Round 6
// 148.419 us; speedup vs baseline: 1.0944x; 1.0556x over previous
//
#include <hip/hip_runtime.h>
#include <hip/hip_bf16.h>

// All inputs/outputs fp32 (established rounds 1-2).
constexpr int B = 2, S = 2048, E = 1024, H = 16, D = 64;
constexpr int E4 = E / 4;  // 256 float4 per row

// ---------------------------------------------------------------------------
// K1: q_vec[b*E + n] = x[b,S-1,:] . Wq[n,:]
// grid 256 x 256; block = (b, 8 consecutive n); 32-lane e-split. (r3 proven)
__global__ void k_qvec(const float4* __restrict__ x, const float4* __restrict__ Wq,
                       float* __restrict__ q_vec) {
  int blk = blockIdx.x;
  int b = blk >> 7, n0 = (blk & 127) * 8;
  int tid = threadIdx.x;
  int nl = tid >> 5, es = tid & 31;
  const float4* xr = x + ((size_t)b * S + (S - 1)) * E4;
  const float4* wr = Wq + (size_t)(n0 + nl) * E4;
  float acc = 0.f;
#pragma unroll
  for (int j = 0; j < 8; ++j) {
    float4 a = xr[es + 32 * j];
    float4 w = wr[es + 32 * j];
    acc += a.x * w.x + a.y * w.y + a.z * w.z + a.w * w.w;
  }
#pragma unroll
  for (int o = 16; o > 0; o >>= 1) acc += __shfl_xor(acc, o, 64);
  if (es == 0) q_vec[b * E + n0 + nl] = acc;
}

// ---------------------------------------------------------------------------
// K2: wkq[b,h,e] = sum_d q_vec[b,h*D+d] * Wk[h*D+d,e]; zeroes rowsum.
// grid 256 = (bh, 8 eo) x 128 thr. (r3 proven)
__global__ void k_wkq(const float* __restrict__ q_vec, const float* __restrict__ Wk,
                      float* __restrict__ wkq, float* __restrict__ rowsum) {
  int blk = blockIdx.x;
  int eo = blk & 7;
  int bh = blk >> 3;
  int h = bh & 15;
  int tid = threadIdx.x;
  __shared__ float qh[D];
  if (tid < D) qh[tid] = q_vec[(bh >> 4) * E + h * D + tid];
  if (eo == 0 && tid == 0) rowsum[bh] = 0.f;
  __syncthreads();
  int e = eo * 128 + tid;
  const float* wp = Wk + (size_t)h * D * E + e;
  float acc = 0.f;
#pragma unroll 8
  for (int d = 0; d < D; ++d) acc += qh[d] * wp[(size_t)d * E];
  wkq[(size_t)bh * E + e] = acc;
}

// ---------------------------------------------------------------------------
// K3: p[b,h,k] = exp(embK[b,k,:] . wkq[b,h,:]) + per-row sums. (r5 proven)
// grid 256 = (b, 128 k-tiles of 16) x 128 thr; 2 embK rows/thread in regs.
__global__ __launch_bounds__(128) void k_scores_exp(const float4* __restrict__ embK,
                                                    const float4* __restrict__ wkq4,
                                                    float* __restrict__ p,
                                                    float* __restrict__ rowsum) {
  __shared__ float4 wl[H * E4];  // 64 KB
  __shared__ float hsum[16];
  int blk = blockIdx.x;
  int b = blk >> 7, k0 = (blk & 127) * 16;
  int tid = threadIdx.x;
#pragma unroll
  for (int j = 0; j < 32; ++j)
    wl[j * 128 + tid] = wkq4[(size_t)b * (H * E4) + j * 128 + tid];
  if (tid < 16) hsum[tid] = 0.f;
  __syncthreads();
  int kp = tid >> 4, es = tid & 15;
  int ka = k0 + kp, kb = k0 + 8 + kp;
  const float4* ea = embK + ((size_t)b * S + ka) * E4;
  const float4* eb = embK + ((size_t)b * S + kb) * E4;
  float4 va[16], vb[16];
#pragma unroll
  for (int j = 0; j < 16; ++j) { va[j] = ea[es + 16 * j]; vb[j] = eb[es + 16 * j]; }
#pragma unroll 1
  for (int h = 0; h < H; ++h) {
    float aa = 0.f, ab = 0.f;
#pragma unroll
    for (int j = 0; j < 16; ++j) {
      float4 w = wl[h * 256 + es + 16 * j];
      aa += va[j].x * w.x + va[j].y * w.y + va[j].z * w.z + va[j].w * w.w;
      ab += vb[j].x * w.x + vb[j].y * w.y + vb[j].z * w.z + vb[j].w * w.w;
    }
#pragma unroll
    for (int o = 8; o > 0; o >>= 1) {
      aa += __shfl_xor(aa, o, 64);
      ab += __shfl_xor(ab, o, 64);
    }
    if (es == 0) {
      float pa = __expf(aa), pb = __expf(ab);
      float* pr = p + ((size_t)(b * H + h)) * S;
      pr[ka] = pa;
      pr[kb] = pb;
      atomicAdd(&hsum[h], pa + pb);
    }
  }
  __syncthreads();
  if (tid < 16) atomicAdd(&rowsum[b * H + tid], hsum[tid]);
}

// ---------------------------------------------------------------------------
// K4: deterministic partial ctx, 256 blocks (was 128).
// grid (B, 8, 16) x 256: e4-slice of 32 x k-chunk of 128; 8 half-waves split
// the chunk (16 k each); shfl_xor(32) pairs them -> 4 partials/block,
// pz = kz*4 + wave. part: 64 x B*H*E floats (8 MB).
__global__ __launch_bounds__(256) void k_ctx_part(const float4* __restrict__ embV,
                                                  const float* __restrict__ p,
                                                  const float* __restrict__ rowsum,
                                                  float4* __restrict__ part) {
  int b = blockIdx.x, eo = blockIdx.y, kz = blockIdx.z;
  int tid = threadIdx.x;
  int e4l = tid & 31, ksub = tid >> 5;  // 8 half-waves
  int k0 = kz * 128;
  __shared__ float pl[16 * 128];  // 8 KB
  __shared__ float sinv[16];
  if (tid < 16) sinv[tid] = 1.f / rowsum[b * H + tid];
  __syncthreads();
  for (int i = tid; i < 16 * 128; i += 256) {
    int h = i >> 7, kk = i & 127;
    pl[i] = p[((size_t)(b * H + h)) * S + k0 + kk] * sinv[h];
  }
  __syncthreads();
  int e4 = eo * 32 + e4l;
  float4 acc[H];
#pragma unroll
  for (int h = 0; h < H; ++h) acc[h] = make_float4(0.f, 0.f, 0.f, 0.f);
  int kb = ksub * 16;
  for (int i = 0; i < 16; ++i) {
    int kk = kb + i;
    float4 v = embV[((size_t)b * S + k0 + kk) * E4 + e4];
#pragma unroll
    for (int h = 0; h < H; ++h) {
      float pv = pl[h * 128 + kk];  // half-wave-uniform address (2 addrs/wave)
      acc[h].x += pv * v.x; acc[h].y += pv * v.y;
      acc[h].z += pv * v.z; acc[h].w += pv * v.w;
    }
  }
  // combine ksub pairs within each wave: lanes 0..31 (+) lanes 32..63
#pragma unroll
  for (int h = 0; h < H; ++h) {
    acc[h].x += __shfl_xor(acc[h].x, 32, 64);
    acc[h].y += __shfl_xor(acc[h].y, 32, 64);
    acc[h].z += __shfl_xor(acc[h].z, 32, 64);
    acc[h].w += __shfl_xor(acc[h].w, 32, 64);
  }
  if ((tid & 63) < 32) {
    int pz = kz * 4 + (tid >> 6);
#pragma unroll
    for (int h = 0; h < H; ++h)
      part[((size_t)(pz * B + b) * H + h) * E4 + e4] = acc[h];
  }
}

// ---------------------------------------------------------------------------
// K5: reduce 64 partials -> ctx. grid (B, H, 8) x 128 thr.
// Block (b,h,eo): e4-slice of 32; 4 psub-groups of 16 partials, LDS combine.
__global__ __launch_bounds__(128) void k_reduce(const float4* __restrict__ part,
                                                float4* __restrict__ ctx4) {
  int b = blockIdx.x, h = blockIdx.y, eo = blockIdx.z;
  int tid = threadIdx.x;
  int e4l = tid & 31, psub = tid >> 5;
  int e4 = eo * 32 + e4l;
  const size_t pstride = (size_t)B * H * E4;
  const float4* pp = part + ((size_t)b * H + h) * E4 + e4 + psub * 16 * pstride;
  float4 acc = make_float4(0.f, 0.f, 0.f, 0.f);
#pragma unroll
  for (int j = 0; j < 16; ++j) {
    float4 c = pp[j * pstride];
    acc.x += c.x; acc.y += c.y; acc.z += c.z; acc.w += c.w;
  }
  __shared__ float4 red[128];
  red[tid] = acc;
  __syncthreads();
  if (tid < 32) {
    float4 a0 = red[tid], a1 = red[tid + 32], a2 = red[tid + 64], a3 = red[tid + 96];
    float4 r = make_float4(a0.x + a1.x + a2.x + a3.x, a0.y + a1.y + a2.y + a3.y,
                           a0.z + a1.z + a2.z + a3.z, a0.w + a1.w + a2.w + a3.w);
    ctx4[((size_t)b * H + h) * E4 + e4] = r;
  }
}

// ---------------------------------------------------------------------------
// K6: o_vec[b*E+n] = ctx[b, n/64, :] . Wv[n,:]  (wave per n; ctx is L2-hot)
__global__ void k_ovec_wave(const float* __restrict__ ctx, const float4* __restrict__ Wv4,
                            float* __restrict__ o_vec) {
  int gw = (blockIdx.x * blockDim.x + threadIdx.x) >> 6;
  int lane = threadIdx.x & 63;
  int b = gw >> 10, nn = gw & 1023;
  const float4* xr = (const float4*)(ctx + ((size_t)(b * H + (nn >> 6))) * E);
  const float4* wr = Wv4 + (size_t)nn * E4;
  float acc = 0.f;
#pragma unroll
  for (int j = 0; j < 4; ++j) {
    float4 a = xr[lane + 64 * j];
    float4 w = wr[lane + 64 * j];
    acc += a.x * w.x + a.y * w.y + a.z * w.z + a.w * w.w;
  }
#pragma unroll
  for (int o = 32; o > 0; o >>= 1) acc += __shfl_xor(acc, o, 64);
  if (lane == 0) o_vec[gw] = acc;
}

// ---------------------------------------------------------------------------
// K7: out_vec[b*E+n] = o_vec[b,:] . Wo[n,:]  (wave per n)
__global__ void k_outvec(const float* __restrict__ o_vec, const float4* __restrict__ Wo4,
                         float* __restrict__ out_vec) {
  int gw = (blockIdx.x * blockDim.x + threadIdx.x) >> 6;
  int lane = threadIdx.x & 63;
  int b = gw >> 10, nn = gw & 1023;
  const float4* xr = (const float4*)(o_vec + (size_t)b * E);
  const float4* wr = Wo4 + (size_t)nn * E4;
  float acc = 0.f;
#pragma unroll
  for (int j = 0; j < 4; ++j) {
    float4 a = xr[lane + 64 * j];
    float4 w = wr[lane + 64 * j];
    acc += a.x * w.x + a.y * w.y + a.z * w.z + a.w * w.w;
  }
#pragma unroll
  for (int o = 32; o > 0; o >>= 1) acc += __shfl_xor(acc, o, 64);
  if (lane == 0) out_vec[gw] = acc;
}

// ---------------------------------------------------------------------------
// K8: broadcast out_vec over all S rows (float4, write-bound ~2.7 us).
__global__ void k_bcast(const float4* __restrict__ ov4, float4* __restrict__ out4) {
  int base = blockIdx.x * 1024 + threadIdx.x;
#pragma unroll
  for (int r = 0; r < 4; ++r) {
    int g = base + r * 256;
    out4[g] = ov4[(g >> 19) * E4 + (g & 255)];
  }
}

// ---------------------------------------------------------------------------
extern "C" void kernel_launch(void* const* d_in, const int* in_sizes, int n_in,
                              void* d_out, int out_size, void* d_ws, size_t ws_size,
                              hipStream_t stream) {
  const float* inputs = (const float*)d_in[0];
  const float* embV   = (const float*)d_in[1];
  const float* embK   = (const float*)d_in[2];
  const float* Wq     = (const float*)d_in[3];
  const float* Wk     = (const float*)d_in[4];
  const float* Wv     = (const float*)d_in[5];
  const float* Wo     = (const float*)d_in[6];

  float* ws      = (float*)d_ws;
  float* q_vec   = ws;                    // 2048
  float* wkq     = q_vec + B * E;         // 32768
  float* p       = wkq + B * H * E;       // 65536 (exp scores)
  float* rowsum  = p + B * H * S;         // 32 (pad to 64)
  float* o_vec   = rowsum + 64;           // 2048
  float* out_vec = o_vec + B * E;         // 2048
  float* part    = out_vec + B * E;       // 64*B*H*E = 2097152 (8 MB)
  float* ctx     = part + 64 * B * H * E; // 32768

  k_qvec<<<256, 256, 0, stream>>>((const float4*)inputs, (const float4*)Wq, q_vec);
  k_wkq<<<256, 128, 0, stream>>>(q_vec, Wk, wkq, rowsum);
  k_scores_exp<<<256, 128, 0, stream>>>((const float4*)embK, (const float4*)wkq,
                                        p, rowsum);
  k_ctx_part<<<dim3(B, 8, 16), 256, 0, stream>>>((const float4*)embV, p, rowsum,
                                                 (float4*)part);
  k_reduce<<<dim3(B, H, 8), 128, 0, stream>>>((const float4*)part, (float4*)ctx);
  k_ovec_wave<<<512, 256, 0, stream>>>(ctx, (const float4*)Wv, o_vec);
  k_outvec<<<512, 256, 0, stream>>>(o_vec, (const float4*)Wo, out_vec);
  k_bcast<<<1024, 256, 0, stream>>>((const float4*)out_vec, (float4*)d_out);
}

// Round 7
// 144.656 us; speedup vs baseline: 1.1228x; 1.0260x over previous
//
#include <hip/hip_runtime.h>
#include <hip/hip_bf16.h>

// All inputs/outputs fp32 (established rounds 1-2).
constexpr int B = 2, S = 2048, E = 1024, H = 16, D = 64;
constexpr int E4 = E / 4;  // 256 float4 per row

// ---------------------------------------------------------------------------
// K1: q_vec[b*E + n] = x[b,S-1,:] . Wq[n,:]
// grid 256 x 256; block = (b, 8 consecutive n); 32-lane e-split. (r3 proven)
__global__ void k_qvec(const float4* __restrict__ x, const float4* __restrict__ Wq,
                       float* __restrict__ q_vec) {
  int blk = blockIdx.x;
  int b = blk >> 7, n0 = (blk & 127) * 8;
  int tid = threadIdx.x;
  int nl = tid >> 5, es = tid & 31;
  const float4* xr = x + ((size_t)b * S + (S - 1)) * E4;
  const float4* wr = Wq + (size_t)(n0 + nl) * E4;
  float acc = 0.f;
#pragma unroll
  for (int j = 0; j < 8; ++j) {
    float4 a = xr[es + 32 * j];
    float4 w = wr[es + 32 * j];
    acc += a.x * w.x + a.y * w.y + a.z * w.z + a.w * w.w;
  }
#pragma unroll
  for (int o = 16; o > 0; o >>= 1) acc += __shfl_xor(acc, o, 64);
  if (es == 0) q_vec[b * E + n0 + nl] = acc;
}

// ---------------------------------------------------------------------------
// K2: wkq[b,h,e] = sum_d q_vec[b,h*D+d] * Wk[h*D+d,e]; zeroes rowsum.
// grid 256 = (bh, 8 eo) x 128 thr. (r3 proven)
__global__ void k_wkq(const float* __restrict__ q_vec, const float* __restrict__ Wk,
                      float* __restrict__ wkq, float* __restrict__ rowsum) {
  int blk = blockIdx.x;
  int eo = blk & 7;
  int bh = blk >> 3;
  int h = bh & 15;
  int tid = threadIdx.x;
  __shared__ float qh[D];
  if (tid < D) qh[tid] = q_vec[(bh >> 4) * E + h * D + tid];
  if (eo == 0 && tid == 0) rowsum[bh] = 0.f;
  __syncthreads();
  int e = eo * 128 + tid;
  const float* wp = Wk + (size_t)h * D * E + e;
  float acc = 0.f;
#pragma unroll 8
  for (int d = 0; d < D; ++d) acc += qh[d] * wp[(size_t)d * E];
  wkq[(size_t)bh * E + e] = acc;
}

// ---------------------------------------------------------------------------
// K3: p[b,h,k] = exp(embK[b,k,:] . wkq[b,h,:]) + per-row sums. (r5 proven)
// grid 256 = (b, 128 k-tiles of 16) x 128 thr; 2 embK rows/thread in regs.
__global__ __launch_bounds__(128) void k_scores_exp(const float4* __restrict__ embK,
                                                    const float4* __restrict__ wkq4,
                                                    float* __restrict__ p,
                                                    float* __restrict__ rowsum) {
  __shared__ float4 wl[H * E4];  // 64 KB
  __shared__ float hsum[16];
  int blk = blockIdx.x;
  int b = blk >> 7, k0 = (blk & 127) * 16;
  int tid = threadIdx.x;
#pragma unroll
  for (int j = 0; j < 32; ++j)
    wl[j * 128 + tid] = wkq4[(size_t)b * (H * E4) + j * 128 + tid];
  if (tid < 16) hsum[tid] = 0.f;
  __syncthreads();
  int kp = tid >> 4, es = tid & 15;
  int ka = k0 + kp, kb = k0 + 8 + kp;
  const float4* ea = embK + ((size_t)b * S + ka) * E4;
  const float4* eb = embK + ((size_t)b * S + kb) * E4;
  float4 va[16], vb[16];
#pragma unroll
  for (int j = 0; j < 16; ++j) { va[j] = ea[es + 16 * j]; vb[j] = eb[es + 16 * j]; }
#pragma unroll 1
  for (int h = 0; h < H; ++h) {
    float aa = 0.f, ab = 0.f;
#pragma unroll
    for (int j = 0; j < 16; ++j) {
      float4 w = wl[h * 256 + es + 16 * j];
      aa += va[j].x * w.x + va[j].y * w.y + va[j].z * w.z + va[j].w * w.w;
      ab += vb[j].x * w.x + vb[j].y * w.y + vb[j].z * w.z + vb[j].w * w.w;
    }
#pragma unroll
    for (int o = 8; o > 0; o >>= 1) {
      aa += __shfl_xor(aa, o, 64);
      ab += __shfl_xor(ab, o, 64);
    }
    if (es == 0) {
      float pa = __expf(aa), pb = __expf(ab);
      float* pr = p + ((size_t)(b * H + h)) * S;
      pr[ka] = pa;
      pr[kb] = pb;
      atomicAdd(&hsum[h], pa + pb);
    }
  }
  __syncthreads();
  if (tid < 16) atomicAdd(&rowsum[b * H + tid], hsum[tid]);
}

// ---------------------------------------------------------------------------
// K4: deterministic UNNORMALIZED partial ctx; 32 partials (4 MB, was 8).
// grid (B, 16, 8) x 256: e4-slice of 16 x k-chunk of 256. 16 ks-groups of
// 16 k each; wave = 4 ks-groups, combined via shfl_xor(16,32) -> 1 partial
// per wave, pz = kz*4 + wave in [0,32).
__global__ __launch_bounds__(256) void k_ctx_part(const float4* __restrict__ embV,
                                                  const float* __restrict__ p,
                                                  float4* __restrict__ part) {
  int b = blockIdx.x, eo = blockIdx.y, kz = blockIdx.z;
  int tid = threadIdx.x;
  int e4l = tid & 15, ks = tid >> 4;  // 16 ks-groups
  int k0 = kz * 256;
  __shared__ float pl[16 * 256];  // 16 KB
  for (int i = tid; i < 16 * 256; i += 256) {
    int h = i >> 8, kk = i & 255;
    pl[i] = p[((size_t)(b * H + h)) * S + k0 + kk];
  }
  __syncthreads();
  int e4 = eo * 16 + e4l;
  float4 acc[H];
#pragma unroll
  for (int h = 0; h < H; ++h) acc[h] = make_float4(0.f, 0.f, 0.f, 0.f);
  for (int i = 0; i < 16; ++i) {
    int kk = ks + 16 * i;
    float4 v = embV[((size_t)b * S + k0 + kk) * E4 + e4];
#pragma unroll
    for (int h = 0; h < H; ++h) {
      float pv = pl[h * 256 + kk];  // 4 distinct consecutive words/wave: no conflict
      acc[h].x += pv * v.x; acc[h].y += pv * v.y;
      acc[h].z += pv * v.z; acc[h].w += pv * v.w;
    }
  }
  // combine the wave's 4 ks-groups (lane bits 4,5): total over 64 k
#pragma unroll
  for (int h = 0; h < H; ++h) {
    acc[h].x += __shfl_xor(acc[h].x, 16, 64);
    acc[h].y += __shfl_xor(acc[h].y, 16, 64);
    acc[h].z += __shfl_xor(acc[h].z, 16, 64);
    acc[h].w += __shfl_xor(acc[h].w, 16, 64);
    acc[h].x += __shfl_xor(acc[h].x, 32, 64);
    acc[h].y += __shfl_xor(acc[h].y, 32, 64);
    acc[h].z += __shfl_xor(acc[h].z, 32, 64);
    acc[h].w += __shfl_xor(acc[h].w, 32, 64);
  }
  int lane = tid & 63, w = tid >> 6;
  if (lane < 16) {
    int pz = kz * 4 + w;
#pragma unroll
    for (int h = 0; h < H; ++h)
      part[((size_t)(pz * B + b) * H + h) * E4 + e4] = acc[h];
  }
}

// ---------------------------------------------------------------------------
// K5: reduce 32 partials -> ctx (unnormalized). grid (B, H, 8) x 128 thr.
__global__ __launch_bounds__(128) void k_reduce(const float4* __restrict__ part,
                                                float4* __restrict__ ctx4) {
  int b = blockIdx.x, h = blockIdx.y, eo = blockIdx.z;
  int tid = threadIdx.x;
  int e4l = tid & 31, psub = tid >> 5;  // 4 psub-groups of 8 partials
  int e4 = eo * 32 + e4l;
  const size_t pstride = (size_t)B * H * E4;
  const float4* pp = part + ((size_t)b * H + h) * E4 + e4 + (size_t)psub * 8 * pstride;
  float4 acc = make_float4(0.f, 0.f, 0.f, 0.f);
#pragma unroll
  for (int j = 0; j < 8; ++j) {
    float4 c = pp[j * pstride];
    acc.x += c.x; acc.y += c.y; acc.z += c.z; acc.w += c.w;
  }
  __shared__ float4 red[128];
  red[tid] = acc;
  __syncthreads();
  if (tid < 32) {
    float4 a0 = red[tid], a1 = red[tid + 32], a2 = red[tid + 64], a3 = red[tid + 96];
    float4 r = make_float4(a0.x + a1.x + a2.x + a3.x, a0.y + a1.y + a2.y + a3.y,
                           a0.z + a1.z + a2.z + a3.z, a0.w + a1.w + a2.w + a3.w);
    ctx4[((size_t)b * H + h) * E4 + e4] = r;
  }
}

// ---------------------------------------------------------------------------
// K6: o_vec[b*E+n] = (ctx[b,n/64,:]/rowsum[b,n/64]) . Wv[n,:]  (wave per n)
__global__ void k_ovec_wave(const float* __restrict__ ctx, const float4* __restrict__ Wv4,
                            const float* __restrict__ rowsum, float* __restrict__ o_vec) {
  int gw = (blockIdx.x * blockDim.x + threadIdx.x) >> 6;
  int lane = threadIdx.x & 63;
  int b = gw >> 10, nn = gw & 1023;
  int bh = b * H + (nn >> 6);
  const float4* xr = (const float4*)(ctx + (size_t)bh * E);
  const float4* wr = Wv4 + (size_t)nn * E4;
  float acc = 0.f;
#pragma unroll
  for (int j = 0; j < 4; ++j) {
    float4 a = xr[lane + 64 * j];
    float4 w = wr[lane + 64 * j];
    acc += a.x * w.x + a.y * w.y + a.z * w.z + a.w * w.w;
  }
#pragma unroll
  for (int o = 32; o > 0; o >>= 1) acc += __shfl_xor(acc, o, 64);
  if (lane == 0) o_vec[gw] = acc / rowsum[bh];  // deferred softmax normalization
}

// ---------------------------------------------------------------------------
// K7: out_vec[b*E+n] = o_vec[b,:] . Wo[n,:]  (wave per n)
__global__ void k_outvec(const float* __restrict__ o_vec, const float4* __restrict__ Wo4,
                         float* __restrict__ out_vec) {
  int gw = (blockIdx.x * blockDim.x + threadIdx.x) >> 6;
  int lane = threadIdx.x & 63;
  int b = gw >> 10, nn = gw & 1023;
  const float4* xr = (const float4*)(o_vec + (size_t)b * E);
  const float4* wr = Wo4 + (size_t)nn * E4;
  float acc = 0.f;
#pragma unroll
  for (int j = 0; j < 4; ++j) {
    float4 a = xr[lane + 64 * j];
    float4 w = wr[lane + 64 * j];
    acc += a.x * w.x + a.y * w.y + a.z * w.z + a.w * w.w;
  }
#pragma unroll
  for (int o = 32; o > 0; o >>= 1) acc += __shfl_xor(acc, o, 64);
  if (lane == 0) out_vec[gw] = acc;
}

// ---------------------------------------------------------------------------
// K8: broadcast out_vec over all S rows (float4, write-bound).
__global__ void k_bcast(const float4* __restrict__ ov4, float4* __restrict__ out4) {
  int base = blockIdx.x * 1024 + threadIdx.x;
#pragma unroll
  for (int r = 0; r < 4; ++r) {
    int g = base + r * 256;
    out4[g] = ov4[(g >> 19) * E4 + (g & 255)];
  }
}

// ---------------------------------------------------------------------------
extern "C" void kernel_launch(void* const* d_in, const int* in_sizes, int n_in,
                              void* d_out, int out_size, void* d_ws, size_t ws_size,
                              hipStream_t stream) {
  const float* inputs = (const float*)d_in[0];
  const float* embV   = (const float*)d_in[1];
  const float* embK   = (const float*)d_in[2];
  const float* Wq     = (const float*)d_in[3];
  const float* Wk     = (const float*)d_in[4];
  const float* Wv     = (const float*)d_in[5];
  const float* Wo     = (const float*)d_in[6];

  float* ws      = (float*)d_ws;
  float* q_vec   = ws;                    // 2048
  float* wkq     = q_vec + B * E;         // 32768
  float* p       = wkq + B * H * E;       // 65536 (exp scores, unnormalized)
  float* rowsum  = p + B * H * S;         // 32 (pad to 64)
  float* o_vec   = rowsum + 64;           // 2048
  float* out_vec = o_vec + B * E;         // 2048
  float* part    = out_vec + B * E;       // 32*B*H*E = 1048576 (4 MB)
  float* ctx     = part + 32 * B * H * E; // 32768

  k_qvec<<<256, 256, 0, stream>>>((const float4*)inputs, (const float4*)Wq, q_vec);
  k_wkq<<<256, 128, 0, stream>>>(q_vec, Wk, wkq, rowsum);
  k_scores_exp<<<256, 128, 0, stream>>>((const float4*)embK, (const float4*)wkq,
                                        p, rowsum);
  k_ctx_part<<<dim3(B, 16, 8), 256, 0, stream>>>((const float4*)embV, p, (float4*)part);
  k_reduce<<<dim3(B, H, 8), 128, 0, stream>>>((const float4*)part, (float4*)ctx);
  k_ovec_wave<<<512, 256, 0, stream>>>(ctx, (const float4*)Wv, rowsum, o_vec);
  k_outvec<<<512, 256, 0, stream>>>(o_vec, (const float4*)Wo, out_vec);
  k_bcast<<<1024, 256, 0, stream>>>((const float4*)out_vec, (float4*)d_out);
}

// Round 8
// 142.377 us; speedup vs baseline: 1.1408x; 1.0160x over previous
//
#include <hip/hip_runtime.h>
#include <hip/hip_bf16.h>

// All inputs/outputs fp32 (established rounds 1-2).
constexpr int B = 2, S = 2048, E = 1024, H = 16, D = 64;
constexpr int E4 = E / 4;  // 256 float4 per row

__device__ __forceinline__ float dot4(float4 a, float4 w) {
  return a.x * w.x + a.y * w.y + a.z * w.z + a.w * w.w;
}

// ---------------------------------------------------------------------------
// K1: q_vec[b*E + n] = x[b,S-1,:] . Wq[n,:]
// grid 256 x 256; block = (b, 8 consecutive n); 32-lane e-split. (r3 proven)
__global__ void k_qvec(const float4* __restrict__ x, const float4* __restrict__ Wq,
                       float* __restrict__ q_vec) {
  int blk = blockIdx.x;
  int b = blk >> 7, n0 = (blk & 127) * 8;
  int tid = threadIdx.x;
  int nl = tid >> 5, es = tid & 31;
  const float4* xr = x + ((size_t)b * S + (S - 1)) * E4;
  const float4* wr = Wq + (size_t)(n0 + nl) * E4;
  float acc = 0.f;
#pragma unroll
  for (int j = 0; j < 8; ++j) {
    float4 a = xr[es + 32 * j];
    float4 w = wr[es + 32 * j];
    acc += dot4(a, w);
  }
#pragma unroll
  for (int o = 16; o > 0; o >>= 1) acc += __shfl_xor(acc, o, 64);
  if (es == 0) q_vec[b * E + n0 + nl] = acc;
}

// ---------------------------------------------------------------------------
// K2: wkq[b,h,e] = sum_d q_vec[b,h*D+d] * Wk[h*D+d,e]; zeroes rowsum.
// grid 256 = (bh, 8 eo) x 128 thr. (r3 proven)
__global__ void k_wkq(const float* __restrict__ q_vec, const float* __restrict__ Wk,
                      float* __restrict__ wkq, float* __restrict__ rowsum) {
  int blk = blockIdx.x;
  int eo = blk & 7;
  int bh = blk >> 3;
  int h = bh & 15;
  int tid = threadIdx.x;
  __shared__ float qh[D];
  if (tid < D) qh[tid] = q_vec[(bh >> 4) * E + h * D + tid];
  if (eo == 0 && tid == 0) rowsum[bh] = 0.f;
  __syncthreads();
  int e = eo * 128 + tid;
  const float* wp = Wk + (size_t)h * D * E + e;
  float acc = 0.f;
#pragma unroll 8
  for (int d = 0; d < D; ++d) acc += qh[d] * wp[(size_t)d * E];
  wkq[(size_t)bh * E + e] = acc;
}

// ---------------------------------------------------------------------------
// K3: p[b,h,k] = exp(embK[b,k,:] . wkq[b,h,:]) + per-row sums.
// v3: 4 embK rows/thread so each wl ds_read_b128 feeds 4 FMAs (128 b128/thr,
// was 256). grid 256 = (b, 128 k-tiles of 16) x 128 thr; thread = (kp of 4,
// es of 32); rows k0+kp+{0,4,8,12}.
__global__ __launch_bounds__(128) void k_scores_exp(const float4* __restrict__ embK,
                                                    const float4* __restrict__ wkq4,
                                                    float* __restrict__ p,
                                                    float* __restrict__ rowsum) {
  __shared__ float4 wl[H * E4];  // 64 KB
  __shared__ float hsum[16];
  int blk = blockIdx.x;
  int b = blk >> 7, k0 = (blk & 127) * 16;
  int tid = threadIdx.x;
#pragma unroll
  for (int j = 0; j < 32; ++j)
    wl[j * 128 + tid] = wkq4[(size_t)b * (H * E4) + j * 128 + tid];
  if (tid < 16) hsum[tid] = 0.f;
  __syncthreads();
  int kp = tid >> 5, es = tid & 31;
  const float4* e0 = embK + ((size_t)b * S + k0 + kp) * E4;
  const float4* e1 = embK + ((size_t)b * S + k0 + kp + 4) * E4;
  const float4* e2 = embK + ((size_t)b * S + k0 + kp + 8) * E4;
  const float4* e3 = embK + ((size_t)b * S + k0 + kp + 12) * E4;
  float4 va[8], vb[8], vc[8], vd[8];
#pragma unroll
  for (int j = 0; j < 8; ++j) {
    va[j] = e0[es + 32 * j]; vb[j] = e1[es + 32 * j];
    vc[j] = e2[es + 32 * j]; vd[j] = e3[es + 32 * j];
  }
#pragma unroll 1
  for (int h = 0; h < H; ++h) {
    float aa = 0.f, ab = 0.f, ac = 0.f, ad = 0.f;
#pragma unroll
    for (int j = 0; j < 8; ++j) {
      float4 w = wl[h * 256 + es + 32 * j];
      aa += dot4(va[j], w); ab += dot4(vb[j], w);
      ac += dot4(vc[j], w); ad += dot4(vd[j], w);
    }
#pragma unroll
    for (int o = 16; o > 0; o >>= 1) {
      aa += __shfl_xor(aa, o, 64); ab += __shfl_xor(ab, o, 64);
      ac += __shfl_xor(ac, o, 64); ad += __shfl_xor(ad, o, 64);
    }
    if (es == 0) {
      float pa = __expf(aa), pb = __expf(ab), pc = __expf(ac), pd = __expf(ad);
      float* pr = p + ((size_t)(b * H + h)) * S + k0 + kp;
      pr[0] = pa; pr[4] = pb; pr[8] = pc; pr[12] = pd;
      atomicAdd(&hsum[h], (pa + pb) + (pc + pd));
    }
  }
  __syncthreads();
  if (tid < 16) atomicAdd(&rowsum[b * H + tid], hsum[tid]);
}

// ---------------------------------------------------------------------------
// K4: deterministic UNNORMALIZED partial ctx; 32 partials (4 MB).
// v2: blocked kk + float4 pl reads -> each ds_read_b128 of p feeds 16 FMAs
// (64 b128/thr, was 256 b32). grid (B, 16, 8) x 256: e4-slice 16 x k-chunk
// 256; 16 ks-groups of 16 consecutive kk; wave combines its 4 ks-groups via
// shfl_xor(16,32) -> partial over 64 k, pz = kz*4 + wave.
__global__ __launch_bounds__(256) void k_ctx_part(const float4* __restrict__ embV,
                                                  const float* __restrict__ p,
                                                  float4* __restrict__ part) {
  int b = blockIdx.x, eo = blockIdx.y, kz = blockIdx.z;
  int tid = threadIdx.x;
  int e4l = tid & 15, ks = tid >> 4;  // 16 ks-groups, blocked
  int k0 = kz * 256;
  __shared__ float pl[16 * 256];  // pl[h*256 + kk], 16 KB
  for (int i = tid; i < 16 * 256; i += 256) {
    int h = i >> 8, kk = i & 255;
    pl[i] = p[((size_t)(b * H + h)) * S + k0 + kk];
  }
  __syncthreads();
  const float4* pl4 = (const float4*)pl;  // pl4[h*64 + kk/4]
  int e4 = eo * 16 + e4l;
  float4 acc[H];
#pragma unroll
  for (int h = 0; h < H; ++h) acc[h] = make_float4(0.f, 0.f, 0.f, 0.f);
#pragma unroll
  for (int i4 = 0; i4 < 4; ++i4) {
    int kk = ks * 16 + i4 * 4;
    const float4* vb = embV + ((size_t)b * S + k0 + kk) * E4 + e4;
    float4 v0 = vb[0 * E4], v1 = vb[1 * E4], v2 = vb[2 * E4], v3 = vb[3 * E4];
    int kq = kk >> 2;
#pragma unroll
    for (int h = 0; h < H; ++h) {
      float4 p4 = pl4[h * 64 + kq];
      acc[h].x += p4.x * v0.x + p4.y * v1.x + p4.z * v2.x + p4.w * v3.x;
      acc[h].y += p4.x * v0.y + p4.y * v1.y + p4.z * v2.y + p4.w * v3.y;
      acc[h].z += p4.x * v0.z + p4.y * v1.z + p4.z * v2.z + p4.w * v3.z;
      acc[h].w += p4.x * v0.w + p4.y * v1.w + p4.z * v2.w + p4.w * v3.w;
    }
  }
  // combine the wave's 4 ks-groups (lane bits 4,5): total over 64 consecutive k
#pragma unroll
  for (int h = 0; h < H; ++h) {
    acc[h].x += __shfl_xor(acc[h].x, 16, 64);
    acc[h].y += __shfl_xor(acc[h].y, 16, 64);
    acc[h].z += __shfl_xor(acc[h].z, 16, 64);
    acc[h].w += __shfl_xor(acc[h].w, 16, 64);
    acc[h].x += __shfl_xor(acc[h].x, 32, 64);
    acc[h].y += __shfl_xor(acc[h].y, 32, 64);
    acc[h].z += __shfl_xor(acc[h].z, 32, 64);
    acc[h].w += __shfl_xor(acc[h].w, 32, 64);
  }
  int lane = tid & 63, w = tid >> 6;
  if (lane < 16) {
    int pz = kz * 4 + w;
#pragma unroll
    for (int h = 0; h < H; ++h)
      part[((size_t)(pz * B + b) * H + h) * E4 + e4] = acc[h];
  }
}

// ---------------------------------------------------------------------------
// K5: reduce 32 partials -> ctx (unnormalized). grid (B, H, 8) x 128 thr.
__global__ __launch_bounds__(128) void k_reduce(const float4* __restrict__ part,
                                                float4* __restrict__ ctx4) {
  int b = blockIdx.x, h = blockIdx.y, eo = blockIdx.z;
  int tid = threadIdx.x;
  int e4l = tid & 31, psub = tid >> 5;  // 4 psub-groups of 8 partials
  int e4 = eo * 32 + e4l;
  const size_t pstride = (size_t)B * H * E4;
  const float4* pp = part + ((size_t)b * H + h) * E4 + e4 + (size_t)psub * 8 * pstride;
  float4 acc = make_float4(0.f, 0.f, 0.f, 0.f);
#pragma unroll
  for (int j = 0; j < 8; ++j) {
    float4 c = pp[j * pstride];
    acc.x += c.x; acc.y += c.y; acc.z += c.z; acc.w += c.w;
  }
  __shared__ float4 red[128];
  red[tid] = acc;
  __syncthreads();
  if (tid < 32) {
    float4 a0 = red[tid], a1 = red[tid + 32], a2 = red[tid + 64], a3 = red[tid + 96];
    float4 r = make_float4(a0.x + a1.x + a2.x + a3.x, a0.y + a1.y + a2.y + a3.y,
                           a0.z + a1.z + a2.z + a3.z, a0.w + a1.w + a2.w + a3.w);
    ctx4[((size_t)b * H + h) * E4 + e4] = r;
  }
}

// ---------------------------------------------------------------------------
// K6: o_vec[b*E+n] = (ctx[b,n/64,:]/rowsum[b,n/64]) . Wv[n,:]  (wave per n)
__global__ void k_ovec_wave(const float* __restrict__ ctx, const float4* __restrict__ Wv4,
                            const float* __restrict__ rowsum, float* __restrict__ o_vec) {
  int gw = (blockIdx.x * blockDim.x + threadIdx.x) >> 6;
  int lane = threadIdx.x & 63;
  int b = gw >> 10, nn = gw & 1023;
  int bh = b * H + (nn >> 6);
  const float4* xr = (const float4*)(ctx + (size_t)bh * E);
  const float4* wr = Wv4 + (size_t)nn * E4;
  float acc = 0.f;
#pragma unroll
  for (int j = 0; j < 4; ++j) {
    float4 a = xr[lane + 64 * j];
    float4 w = wr[lane + 64 * j];
    acc += dot4(a, w);
  }
#pragma unroll
  for (int o = 32; o > 0; o >>= 1) acc += __shfl_xor(acc, o, 64);
  if (lane == 0) o_vec[gw] = acc / rowsum[bh];  // deferred softmax normalization
}

// ---------------------------------------------------------------------------
// K7: out_vec[b*E+n] = o_vec[b,:] . Wo[n,:]  (wave per n)
__global__ void k_outvec(const float* __restrict__ o_vec, const float4* __restrict__ Wo4,
                         float* __restrict__ out_vec) {
  int gw = (blockIdx.x * blockDim.x + threadIdx.x) >> 6;
  int lane = threadIdx.x & 63;
  int b = gw >> 10, nn = gw & 1023;
  const float4* xr = (const float4*)(o_vec + (size_t)b * E);
  const float4* wr = Wo4 + (size_t)nn * E4;
  float acc = 0.f;
#pragma unroll
  for (int j = 0; j < 4; ++j) {
    float4 a = xr[lane + 64 * j];
    float4 w = wr[lane + 64 * j];
    acc += dot4(a, w);
  }
#pragma unroll
  for (int o = 32; o > 0; o >>= 1) acc += __shfl_xor(acc, o, 64);
  if (lane == 0) out_vec[gw] = acc;
}

// ---------------------------------------------------------------------------
// K8: broadcast out_vec over all S rows (float4, write-bound ~2.6 us floor).
__global__ void k_bcast(const float4* __restrict__ ov4, float4* __restrict__ out4) {
  int base = blockIdx.x * 1024 + threadIdx.x;
#pragma unroll
  for (int r = 0; r < 4; ++r) {
    int g = base + r * 256;
    out4[g] = ov4[(g >> 19) * E4 + (g & 255)];
  }
}

// ---------------------------------------------------------------------------
extern "C" void kernel_launch(void* const* d_in, const int* in_sizes, int n_in,
                              void* d_out, int out_size, void* d_ws, size_t ws_size,
                              hipStream_t stream) {
  const float* inputs = (const float*)d_in[0];
  const float* embV   = (const float*)d_in[1];
  const float* embK   = (const float*)d_in[2];
  const float* Wq     = (const float*)d_in[3];
  const float* Wk     = (const float*)d_in[4];
  const float* Wv     = (const float*)d_in[5];
  const float* Wo     = (const float*)d_in[6];

  float* ws      = (float*)d_ws;
  float* q_vec   = ws;                    // 2048
  float* wkq     = q_vec + B * E;         // 32768
  float* p       = wkq + B * H * E;       // 65536 (exp scores, unnormalized)
  float* rowsum  = p + B * H * S;         // 32 (pad to 64)
  float* o_vec   = rowsum + 64;           // 2048
  float* out_vec = o_vec + B * E;         // 2048
  float* part    = out_vec + B * E;       // 32*B*H*E = 1048576 (4 MB)
  float* ctx     = part + 32 * B * H * E; // 32768

  k_qvec<<<256, 256, 0, stream>>>((const float4*)inputs, (const float4*)Wq, q_vec);
  k_wkq<<<256, 128, 0, stream>>>(q_vec, Wk, wkq, rowsum);
  k_scores_exp<<<256, 128, 0, stream>>>((const float4*)embK, (const float4*)wkq,
                                        p, rowsum);
  k_ctx_part<<<dim3(B, 16, 8), 256, 0, stream>>>((const float4*)embV, p, (float4*)part);
  k_reduce<<<dim3(B, H, 8), 128, 0, stream>>>((const float4*)part, (float4*)ctx);
  k_ovec_wave<<<512, 256, 0, stream>>>(ctx, (const float4*)Wv, rowsum, o_vec);
  k_outvec<<<512, 256, 0, stream>>>(o_vec, (const float4*)Wo, out_vec);
  k_bcast<<<1024, 256, 0, stream>>>((const float4*)out_vec, (float4*)d_out);
}